// Round 1
// baseline (550.890 us; speedup 1.0000x reference)
//
#include <hip/hip_runtime.h>
#include <hip/hip_bf16.h>
#include <cstdint>

// ---------- constants ----------
#define B_      16
#define KLEN_   4096
#define HEADS_  8
#define DMODEL_ 1024
#define DIM_    128
#define KERN_   10

typedef __attribute__((ext_vector_type(8))) short bf16x8;
typedef __attribute__((ext_vector_type(4))) float f32x4;
typedef __attribute__((ext_vector_type(4))) unsigned short u16x4;

__device__ __forceinline__ unsigned short f2bf(float f) {
    unsigned int u = __float_as_uint(f);
    unsigned int r = (u + 0x7fffu + ((u >> 16) & 1u)) >> 16;
    return (unsigned short)r;
}

__device__ __forceinline__ float tanh_fast(float x) {
    // tanh(x) = 1 - 2/(e^{2x}+1); saturates correctly for |x| large
    return 1.0f - 2.0f / (__expf(2.0f * x) + 1.0f);
}

// ---------- K0: transpose w_v (f,e) -> bf16 (e,f) ----------
__global__ __launch_bounds__(256) void wv_transpose_kernel(
        const float* __restrict__ wv, unsigned short* __restrict__ wvT) {
    __shared__ float tile[64][65];
    int f0 = blockIdx.x * 64;
    int e0 = blockIdx.y * 64;
    int t = threadIdx.x;
#pragma unroll
    for (int i = 0; i < 16; ++i) {
        int idx = i * 256 + t;
        int r = idx >> 6, c = idx & 63;
        tile[r][c] = wv[(size_t)(f0 + r) * 1024 + e0 + c];
    }
    __syncthreads();
#pragma unroll
    for (int i = 0; i < 16; ++i) {
        int idx = i * 256 + t;
        int r = idx >> 6, c = idx & 63;   // r = e-local, c = f-local
        wvT[(size_t)(e0 + r) * 1024 + f0 + c] = f2bf(tile[c][r]);
    }
}

// ---------- K1: q projection q[b,h,d] ----------
__global__ __launch_bounds__(128) void qproj_kernel(
        const float* __restrict__ query, const float* __restrict__ w_q,
        float* __restrict__ ws_q) {
    __shared__ float qs[1024];
    int bh = blockIdx.x;
    int b = bh >> 3, h = bh & 7;
    int t = threadIdx.x;
    for (int i = t; i < 1024; i += 128) qs[i] = query[(size_t)b * 1024 + i];
    __syncthreads();
    float acc = 0.f;
    const float* wcol = w_q + h * 128 + t;
    for (int f = 0; f < 1024; ++f) acc += qs[f] * wcol[(size_t)f * 1024];
    ws_q[(size_t)bh * 128 + t] = acc;
}

// ---------- K2: conv1d location features loc[b,c,k] ----------
__global__ __launch_bounds__(256) void loc_conv_kernel(
        const float* __restrict__ pa, const float* __restrict__ conv_w,
        const float* __restrict__ conv_b, float* __restrict__ ws_loc) {
    __shared__ float pas[8][258];
    __shared__ float cw[240];
    __shared__ float cb[16];
    int b = blockIdx.x, k0 = blockIdx.y * 256;
    int t = threadIdx.x;
    for (int i = t; i < 8 * 258; i += 256) {
        int hh = i / 258, kk = i % 258;
        int gk = k0 + kk - 1;
        pas[hh][kk] = (gk >= 0 && gk < 4096) ? pa[((size_t)(b * 8 + hh)) * 4096 + gk] : 0.f;
    }
    if (t < 240) cw[t] = conv_w[t];
    if (t < 10) cb[t] = conv_b[t];
    __syncthreads();
#pragma unroll
    for (int c = 0; c < 10; ++c) {
        float acc = cb[c];
#pragma unroll
        for (int hh = 0; hh < 8; ++hh) {
            float w0 = cw[(c * 8 + hh) * 3 + 0];
            float w1 = cw[(c * 8 + hh) * 3 + 1];
            float w2 = cw[(c * 8 + hh) * 3 + 2];
            acc += pas[hh][t] * w0 + pas[hh][t + 1] * w1 + pas[hh][t + 2] * w2;
        }
        ws_loc[((size_t)(b * 10 + c)) * 4096 + k0 + t] = acc;
    }
}

// ---------- K3: fused bf16 MFMA GEMM (key_in @ w_v) + energy + score ----------
// tile: BM=128 (kk), BN=128 (= one head's DIM), BK=32; 4 waves 2x2
__global__ __launch_bounds__(256) void gemm_score_kernel(
        const float* __restrict__ key_in, const unsigned short* __restrict__ wvT,
        const float* __restrict__ ws_q, const float* __restrict__ ws_loc,
        const float* __restrict__ w_u, const float* __restrict__ bias,
        const float* __restrict__ score_w, const float* __restrict__ score_b,
        float* __restrict__ align_out) {
    __shared__ __align__(16) unsigned short As[128 * 32];
    __shared__ __align__(16) unsigned short Bs[128 * 32];
    __shared__ float loc_sm[10 * 128];
    __shared__ float wu_sm[10 * 128];
    __shared__ float q_sm[128], bias_sm[128], sw_sm[128];
    __shared__ float partial[128 * 2];

    const int t = threadIdx.x;
    const int lane = t & 63, wid = t >> 6;
    const int wm = wid >> 1, wn = wid & 1;

    // XCD-aware swizzle: 8 head-blocks of one A-panel stay on one XCD
    const int fid = blockIdx.x;
    const int x = fid & 7, j = fid >> 3;
    const int bm = x * 64 + (j >> 3);
    const int h = j & 7;
    const int b = bm >> 5;
    const int kk0 = (bm & 31) << 7;

    if (t < 128) {
        q_sm[t] = ws_q[(size_t)(b * 8 + h) * 128 + t];
        bias_sm[t] = bias[t];
        sw_sm[t] = score_w[t];
    }
    for (int i = t; i < 1280; i += 256) {
        int c = i >> 7, r = i & 127;
        loc_sm[i] = ws_loc[((size_t)(b * 10 + c)) * 4096 + kk0 + r];
        wu_sm[i] = w_u[i];
    }

    f32x4 acc[4][4] = {};
    const size_t abase = ((size_t)(b * 4096 + kk0)) * 1024;
    const int e0 = h * 128;

    const int bcol = t >> 2;          // 0..63
    const int bk8 = (t & 3) * 8;      // 0,8,16,24

    for (int kt = 0; kt < 32; ++kt) {
        // stage B (bf16) via async global->LDS, 8KB in 2 waves-worth calls
        {
            const unsigned short* src0 = wvT + (size_t)(e0 + bcol) * 1024 + kt * 32 + bk8;
            const unsigned short* src1 = wvT + (size_t)(e0 + 64 + bcol) * 1024 + kt * 32 + bk8;
            __builtin_amdgcn_global_load_lds(
                (const __attribute__((address_space(1))) void*)src0,
                (__attribute__((address_space(3))) void*)&Bs[t * 8], 16, 0, 0);
            __builtin_amdgcn_global_load_lds(
                (const __attribute__((address_space(1))) void*)src1,
                (__attribute__((address_space(3))) void*)&Bs[2048 + t * 8], 16, 0, 0);
        }
        // stage A: fp32 -> bf16 via registers
        {
            const int r0 = t >> 3;          // 0..31
            const int c4 = (t & 7) * 4;     // 0..28
#pragma unroll
            for (int i = 0; i < 4; ++i) {
                const int row = i * 32 + r0;
                const float4 v = *reinterpret_cast<const float4*>(
                    key_in + abase + (size_t)row * 1024 + kt * 32 + c4);
                u16x4 u;
                u.x = f2bf(v.x); u.y = f2bf(v.y); u.z = f2bf(v.z); u.w = f2bf(v.w);
                *reinterpret_cast<u16x4*>(&As[row * 32 + c4]) = u;
            }
        }
        __syncthreads();

        bf16x8 af[4], bg[4];
#pragma unroll
        for (int mf = 0; mf < 4; ++mf) {
            const int row = wm * 64 + mf * 16 + (lane & 15);
            af[mf] = *reinterpret_cast<const bf16x8*>(&As[row * 32 + (lane >> 4) * 8]);
        }
#pragma unroll
        for (int nf = 0; nf < 4; ++nf) {
            const int col = wn * 64 + nf * 16 + (lane & 15);
            bg[nf] = *reinterpret_cast<const bf16x8*>(&Bs[col * 32 + (lane >> 4) * 8]);
        }
#pragma unroll
        for (int mf = 0; mf < 4; ++mf)
#pragma unroll
            for (int nf = 0; nf < 4; ++nf)
                acc[mf][nf] = __builtin_amdgcn_mfma_f32_16x16x32_bf16(
                    af[mf], bg[nf], acc[mf][nf], 0, 0, 0);
        __syncthreads();
    }

    // epilogue: e = tanh(k + q + tanh(loc@w_u) + bias); score = e . score_w
    const float sb = score_b[0];
#pragma unroll
    for (int mf = 0; mf < 4; ++mf) {
#pragma unroll
        for (int jj = 0; jj < 4; ++jj) {
            const int row_l = wm * 64 + mf * 16 + ((lane >> 4) << 2) + jj;
            float sum = 0.f;
#pragma unroll
            for (int nf = 0; nf < 4; ++nf) {
                const int d = wn * 64 + nf * 16 + (lane & 15);
                float le = 0.f;
#pragma unroll
                for (int c = 0; c < 10; ++c)
                    le += loc_sm[c * 128 + row_l] * wu_sm[c * 128 + d];
                const float xv = acc[mf][nf][jj] + q_sm[d] + bias_sm[d] + tanh_fast(le);
                const float ev = tanh_fast(xv);
                sum += ev * sw_sm[d];
            }
            sum += __shfl_xor(sum, 1);
            sum += __shfl_xor(sum, 2);
            sum += __shfl_xor(sum, 4);
            sum += __shfl_xor(sum, 8);
            if ((lane & 15) == 0) partial[row_l * 2 + wn] = sum;
        }
    }
    __syncthreads();
    if (t < 128) {
        const float s = partial[t * 2] + partial[t * 2 + 1] + sb;
        align_out[(size_t)(b * 8 + h) * 4096 + kk0 + t] = s;
    }
}

// ---------- K4: softmax over k (row of 4096) ----------
__global__ __launch_bounds__(256) void softmax_kernel(float* __restrict__ align_o) {
    const int bh = blockIdx.x;
    float* row = align_o + (size_t)bh * 4096;
    const int t = threadIdx.x;
    float v[16];
    float m = -1e30f;
#pragma unroll
    for (int i = 0; i < 16; ++i) {
        v[i] = row[i * 256 + t];
        m = fmaxf(m, v[i]);
    }
#pragma unroll
    for (int off = 32; off; off >>= 1) m = fmaxf(m, __shfl_xor(m, off));
    __shared__ float sm[4], ss[4];
    const int wid = t >> 6;
    if ((t & 63) == 0) sm[wid] = m;
    __syncthreads();
    m = fmaxf(fmaxf(sm[0], sm[1]), fmaxf(sm[2], sm[3]));
    float s = 0.f;
#pragma unroll
    for (int i = 0; i < 16; ++i) {
        v[i] = __expf(v[i] - m);
        s += v[i];
    }
#pragma unroll
    for (int off = 32; off; off >>= 1) s += __shfl_xor(s, off);
    if ((t & 63) == 0) ss[wid] = s;
    __syncthreads();
    s = ss[0] + ss[1] + ss[2] + ss[3];
    const float inv = 1.f / s;
#pragma unroll
    for (int i = 0; i < 16; ++i) row[i * 256 + t] = v[i] * inv;
}

// ---------- K5: split-K context partials ----------
__global__ __launch_bounds__(256) void ctx_partial_kernel(
        const float* __restrict__ value, const float* __restrict__ align_o,
        float* __restrict__ pctx) {
    const int s = blockIdx.x;    // 0..31
    const int bh = blockIdx.y;   // 0..127
    const int b = bh >> 3, h = bh & 7;
    const int t = threadIdx.x;
    const int d = t & 127, half = t >> 7;
    const float* arow = align_o + (size_t)bh * 4096 + s * 128;
    float acc = 0.f;
    for (int i = 0; i < 64; ++i) {
        const int kk = i * 2 + half;
        acc += arow[kk] * value[((size_t)(b * 4096) + s * 128 + kk) * 1024 + h * 128 + d];
    }
    __shared__ float sm2[256];
    sm2[t] = acc;
    __syncthreads();
    if (t < 128) pctx[((size_t)bh * 32 + s) * 128 + t] = sm2[t] + sm2[t + 128];
}

// ---------- K6: reduce context partials ----------
__global__ __launch_bounds__(128) void ctx_reduce_kernel(
        const float* __restrict__ pctx, float* __restrict__ out) {
    const int bh = blockIdx.x;
    const int t = threadIdx.x;
    float acc = 0.f;
    for (int s2 = 0; s2 < 32; ++s2) acc += pctx[((size_t)bh * 32 + s2) * 128 + t];
    out[(size_t)bh * 128 + t] = acc;
}

extern "C" void kernel_launch(void* const* d_in, const int* in_sizes, int n_in,
                              void* d_out, int out_size, void* d_ws, size_t ws_size,
                              hipStream_t stream) {
    const float* query   = (const float*)d_in[0];
    const float* key_in  = (const float*)d_in[1];
    const float* value   = (const float*)d_in[2];
    const float* pa      = (const float*)d_in[3];
    const float* conv_w  = (const float*)d_in[4];
    const float* conv_b  = (const float*)d_in[5];
    const float* w_u     = (const float*)d_in[6];
    const float* w_q     = (const float*)d_in[7];
    const float* w_v     = (const float*)d_in[8];
    const float* bias    = (const float*)d_in[9];
    const float* score_w = (const float*)d_in[10];
    const float* score_b = (const float*)d_in[11];

    float* out = (float*)d_out;
    float* ctx_out = out;                 // [128,128]
    float* align_out = out + 16384;       // [128,4096]

    char* ws = (char*)d_ws;
    float* ws_q            = (float*)(ws);                               // 64 KB
    float* ws_loc          = (float*)(ws + 65536);                       // 2.62 MB
    unsigned short* ws_wvT = (unsigned short*)(ws + 65536 + 2621440);    // 2 MB
    float* ws_pctx         = (float*)(ws + 65536 + 2621440 + 2097152);   // 2 MB

    hipLaunchKernelGGL(wv_transpose_kernel, dim3(16, 16), dim3(256), 0, stream, w_v, ws_wvT);
    hipLaunchKernelGGL(qproj_kernel, dim3(128), dim3(128), 0, stream, query, w_q, ws_q);
    hipLaunchKernelGGL(loc_conv_kernel, dim3(16, 16), dim3(256), 0, stream, pa, conv_w, conv_b, ws_loc);
    hipLaunchKernelGGL(gemm_score_kernel, dim3(4096), dim3(256), 0, stream,
                       key_in, ws_wvT, ws_q, ws_loc, w_u, bias, score_w, score_b, align_out);
    hipLaunchKernelGGL(softmax_kernel, dim3(128), dim3(256), 0, stream, align_out);
    hipLaunchKernelGGL(ctx_partial_kernel, dim3(32, 128), dim3(256), 0, stream, value, align_out, ws_pctx);
    hipLaunchKernelGGL(ctx_reduce_kernel, dim3(128), dim3(128), 0, stream, ws_pctx, ctx_out);
}

// Round 2
// 456.953 us; speedup vs baseline: 1.2056x; 1.2056x over previous
//
#include <hip/hip_runtime.h>
#include <hip/hip_bf16.h>
#include <cstdint>

typedef __attribute__((ext_vector_type(8))) short bf16x8;
typedef __attribute__((ext_vector_type(4))) float f32x4;
typedef __attribute__((ext_vector_type(4))) unsigned short u16x4;
typedef __attribute__((ext_vector_type(8))) unsigned short u16x8;

__device__ __forceinline__ unsigned short f2bf(float f) {
    unsigned int u = __float_as_uint(f);
    unsigned int r = (u + 0x7fffu + ((u >> 16) & 1u)) >> 16;
    return (unsigned short)r;
}

__device__ __forceinline__ float tanh_fast(float x) {
    return 1.0f - 2.0f / (__expf(2.0f * x) + 1.0f);
}

#define GLDS(SRC, DST) __builtin_amdgcn_global_load_lds(                         \
        (const __attribute__((address_space(1))) void*)(SRC),                    \
        (__attribute__((address_space(3))) void*)(DST), 16, 0, 0)

// ---------- K-1: fp32 -> bf16 bulk convert of key_in ----------
__global__ __launch_bounds__(256) void f32_to_bf16_kernel(
        const float* __restrict__ in, unsigned short* __restrict__ out, int n8) {
    int gid = blockIdx.x * 256 + threadIdx.x;
    int stride = gridDim.x * 256;
    for (int c = gid; c < n8; c += stride) {
        const float4 v0 = *reinterpret_cast<const float4*>(in + (size_t)c * 8);
        const float4 v1 = *reinterpret_cast<const float4*>(in + (size_t)c * 8 + 4);
        u16x8 u;
        u[0] = f2bf(v0.x); u[1] = f2bf(v0.y); u[2] = f2bf(v0.z); u[3] = f2bf(v0.w);
        u[4] = f2bf(v1.x); u[5] = f2bf(v1.y); u[6] = f2bf(v1.z); u[7] = f2bf(v1.w);
        *reinterpret_cast<u16x8*>(out + (size_t)c * 8) = u;
    }
}

// ---------- K0: transpose w_v (f,e) -> bf16 (e,f) ----------
__global__ __launch_bounds__(256) void wv_transpose_kernel(
        const float* __restrict__ wv, unsigned short* __restrict__ wvT) {
    __shared__ float tile[64][65];
    int f0 = blockIdx.x * 64;
    int e0 = blockIdx.y * 64;
    int t = threadIdx.x;
#pragma unroll
    for (int i = 0; i < 16; ++i) {
        int idx = i * 256 + t;
        int r = idx >> 6, c = idx & 63;
        tile[r][c] = wv[(size_t)(f0 + r) * 1024 + e0 + c];
    }
    __syncthreads();
#pragma unroll
    for (int i = 0; i < 16; ++i) {
        int idx = i * 256 + t;
        int r = idx >> 6, c = idx & 63;
        wvT[(size_t)(e0 + r) * 1024 + f0 + c] = f2bf(tile[c][r]);
    }
}

// ---------- K1: q projection ----------
__global__ __launch_bounds__(128) void qproj_kernel(
        const float* __restrict__ query, const float* __restrict__ w_q,
        float* __restrict__ ws_q) {
    __shared__ float qs[1024];
    int bh = blockIdx.x;
    int b = bh >> 3, h = bh & 7;
    int t = threadIdx.x;
    for (int i = t; i < 1024; i += 128) qs[i] = query[(size_t)b * 1024 + i];
    __syncthreads();
    float acc = 0.f;
    const float* wcol = w_q + h * 128 + t;
    for (int f = 0; f < 1024; ++f) acc += qs[f] * wcol[(size_t)f * 1024];
    ws_q[(size_t)bh * 128 + t] = acc;
}

// ---------- K2: conv1d location features ----------
__global__ __launch_bounds__(256) void loc_conv_kernel(
        const float* __restrict__ pa, const float* __restrict__ conv_w,
        const float* __restrict__ conv_b, float* __restrict__ ws_loc) {
    __shared__ float pas[8][258];
    __shared__ float cw[240];
    __shared__ float cb[16];
    int b = blockIdx.x, k0 = blockIdx.y * 256;
    int t = threadIdx.x;
    for (int i = t; i < 8 * 258; i += 256) {
        int hh = i / 258, kk = i % 258;
        int gk = k0 + kk - 1;
        pas[hh][kk] = (gk >= 0 && gk < 4096) ? pa[((size_t)(b * 8 + hh)) * 4096 + gk] : 0.f;
    }
    if (t < 240) cw[t] = conv_w[t];
    if (t < 10) cb[t] = conv_b[t];
    __syncthreads();
#pragma unroll
    for (int c = 0; c < 10; ++c) {
        float acc = cb[c];
#pragma unroll
        for (int hh = 0; hh < 8; ++hh) {
            acc += pas[hh][t] * cw[(c * 8 + hh) * 3 + 0]
                 + pas[hh][t + 1] * cw[(c * 8 + hh) * 3 + 1]
                 + pas[hh][t + 2] * cw[(c * 8 + hh) * 3 + 2];
        }
        ws_loc[((size_t)(b * 10 + c)) * 4096 + k0 + t] = acc;
    }
}

// ---------- K3: fused bf16 MFMA GEMM + energy + score ----------
// BM=128 (keys), BN=128 (one head's DIM), BK=32; 4 waves 2x2; dbuf, 1 barrier/K-step.
// AMODE 0: A pre-converted bf16, staged via global_load_lds.
// AMODE 1: A fp32, reg-convert staging (fallback if ws too small).
template<int AMODE>
__global__ __launch_bounds__(256) void gemm_score_kernel(
        const float* __restrict__ key_f32, const unsigned short* __restrict__ key_bf,
        const unsigned short* __restrict__ wvT,
        const float* __restrict__ ws_q, const float* __restrict__ ws_loc,
        const float* __restrict__ w_u, const float* __restrict__ bias,
        const float* __restrict__ score_w, const float* __restrict__ score_b,
        float* __restrict__ align_out) {
    __shared__ __align__(16) unsigned short As[2][4096];
    __shared__ __align__(16) unsigned short Bs[2][4096];
    __shared__ float loc_sm[1280];
    __shared__ float wu_sm[1280];
    __shared__ float q_sm[128], bias_sm[128], sw_sm[128];
    __shared__ float partial[256];

    const int t = threadIdx.x;
    const int lane = t & 63, wid = t >> 6;
    const int wm = wid >> 1, wn = wid & 1;

    // XCD swizzle: block -> XCD fid%8; 8 head-blocks of one A-panel contiguous on one XCD
    const int fid = blockIdx.x;
    const int x = fid & 7, j = fid >> 3;
    const int bm = x * 64 + (j >> 3);
    const int h = j & 7;
    const int b = bm >> 5;
    const int kk0 = (bm & 31) << 7;

    if (t < 128) {
        q_sm[t] = ws_q[(size_t)(b * 8 + h) * 128 + t];
        bias_sm[t] = bias[t];
        sw_sm[t] = score_w[t];
    }
    for (int i = t; i < 1280; i += 256) {
        int c = i >> 7, r = i & 127;
        loc_sm[i] = ws_loc[((size_t)(b * 10 + c)) * 4096 + kk0 + r];
        wu_sm[i] = w_u[i];
    }

    const int e0 = h * 128;
    const unsigned short* aSrc = key_bf + ((size_t)(b * 4096 + kk0) + (t >> 2)) * 1024 + (t & 3) * 8;
    const unsigned short* bSrc = wvT + (size_t)(e0 + (t >> 2)) * 1024 + (t & 3) * 8;
    const float* aBaseF = key_f32 + ((size_t)(b * 4096 + kk0)) * 1024;

    f32x4 acc[4][4] = {};
    int cur = 0;

#define STAGE_B(BUF, KT) {                                                        \
        GLDS(bSrc + (KT) * 32, &Bs[BUF][t * 8]);                                  \
        GLDS(bSrc + 65536 + (KT) * 32, &Bs[BUF][2048 + t * 8]); }

#define STAGE_A(BUF, KT) {                                                        \
        if (AMODE == 0) {                                                         \
            GLDS(aSrc + (KT) * 32, &As[BUF][t * 8]);                              \
            GLDS(aSrc + 65536 + (KT) * 32, &As[BUF][2048 + t * 8]);               \
        } else {                                                                  \
            const int r0 = t >> 3, c4 = (t & 7) * 4;                              \
            _Pragma("unroll")                                                     \
            for (int i_ = 0; i_ < 4; ++i_) {                                      \
                const int row_ = i_ * 32 + r0;                                    \
                const float4 v_ = *reinterpret_cast<const float4*>(               \
                    aBaseF + (size_t)row_ * 1024 + (KT) * 32 + c4);               \
                u16x4 u_;                                                         \
                u_.x = f2bf(v_.x); u_.y = f2bf(v_.y);                             \
                u_.z = f2bf(v_.z); u_.w = f2bf(v_.w);                             \
                *reinterpret_cast<u16x4*>(&As[BUF][row_ * 32 + c4]) = u_;         \
            }                                                                     \
        } }

    STAGE_A(0, 0);
    STAGE_B(0, 0);
    __syncthreads();

    for (int kt = 0; kt < 32; ++kt) {
        if (kt < 31) {
            STAGE_A(cur ^ 1, kt + 1);
            STAGE_B(cur ^ 1, kt + 1);
        }
        bf16x8 af[4], bg[4];
        const int ko8 = (lane >> 4) * 8;
#pragma unroll
        for (int mf = 0; mf < 4; ++mf) {
            const int row = wm * 64 + mf * 16 + (lane & 15);
            af[mf] = *reinterpret_cast<const bf16x8*>(&As[cur][row * 32 + ko8]);
        }
#pragma unroll
        for (int nf = 0; nf < 4; ++nf) {
            const int col = wn * 64 + nf * 16 + (lane & 15);
            bg[nf] = *reinterpret_cast<const bf16x8*>(&Bs[cur][col * 32 + ko8]);
        }
#pragma unroll
        for (int mf = 0; mf < 4; ++mf)
#pragma unroll
            for (int nf = 0; nf < 4; ++nf)
                acc[mf][nf] = __builtin_amdgcn_mfma_f32_16x16x32_bf16(
                    af[mf], bg[nf], acc[mf][nf], 0, 0, 0);
        __syncthreads();
        cur ^= 1;
    }

    // epilogue: e = tanh(k + q + tanh(loc@w_u) + bias); score = e . score_w
    const float sb = score_b[0];
#pragma unroll
    for (int mf = 0; mf < 4; ++mf) {
#pragma unroll
        for (int jj = 0; jj < 4; ++jj) {
            const int row_l = wm * 64 + mf * 16 + ((lane >> 4) << 2) + jj;
            float sum = 0.f;
#pragma unroll
            for (int nf = 0; nf < 4; ++nf) {
                const int d = wn * 64 + nf * 16 + (lane & 15);
                float le = 0.f;
#pragma unroll
                for (int c = 0; c < 10; ++c)
                    le += loc_sm[c * 128 + row_l] * wu_sm[c * 128 + d];
                const float xv = acc[mf][nf][jj] + q_sm[d] + bias_sm[d] + tanh_fast(le);
                sum += tanh_fast(xv) * sw_sm[d];
            }
            sum += __shfl_xor(sum, 1);
            sum += __shfl_xor(sum, 2);
            sum += __shfl_xor(sum, 4);
            sum += __shfl_xor(sum, 8);
            if ((lane & 15) == 0) partial[row_l * 2 + wn] = sum;
        }
    }
    __syncthreads();
    if (t < 128) {
        align_out[(size_t)(b * 8 + h) * 4096 + kk0 + t] = partial[t * 2] + partial[t * 2 + 1] + sb;
    }
}

// ---------- K4: softmax over k ----------
__global__ __launch_bounds__(256) void softmax_kernel(float* __restrict__ align_o) {
    const int bh = blockIdx.x;
    float* row = align_o + (size_t)bh * 4096;
    const int t = threadIdx.x;
    float v[16];
    float m = -1e30f;
#pragma unroll
    for (int i = 0; i < 16; ++i) {
        v[i] = row[i * 256 + t];
        m = fmaxf(m, v[i]);
    }
#pragma unroll
    for (int off = 32; off; off >>= 1) m = fmaxf(m, __shfl_xor(m, off));
    __shared__ float sm[4], ss[4];
    const int wid = t >> 6;
    if ((t & 63) == 0) sm[wid] = m;
    __syncthreads();
    m = fmaxf(fmaxf(sm[0], sm[1]), fmaxf(sm[2], sm[3]));
    float s = 0.f;
#pragma unroll
    for (int i = 0; i < 16; ++i) {
        v[i] = __expf(v[i] - m);
        s += v[i];
    }
#pragma unroll
    for (int off = 32; off; off >>= 1) s += __shfl_xor(s, off);
    if ((t & 63) == 0) ss[wid] = s;
    __syncthreads();
    s = ss[0] + ss[1] + ss[2] + ss[3];
    const float inv = 1.f / s;
#pragma unroll
    for (int i = 0; i < 16; ++i) row[i * 256 + t] = v[i] * inv;
}

// ---------- K5: split-K context partials (float4) ----------
__global__ __launch_bounds__(256) void ctx_partial_kernel(
        const float* __restrict__ value, const float* __restrict__ align_o,
        float* __restrict__ pctx) {
    const int s = blockIdx.x;    // 0..31
    const int bh = blockIdx.y;   // 0..127
    const int b = bh >> 3, h = bh & 7;
    const int t = threadIdx.x;
    const int d4 = (t & 31) * 4;
    const int kg = t >> 5;       // 0..7
    const float* arow = align_o + (size_t)bh * 4096 + s * 128;
    const float* vbase = value + ((size_t)(b * 4096 + s * 128)) * 1024 + h * 128 + d4;
    float4 acc = {0.f, 0.f, 0.f, 0.f};
    for (int i = 0; i < 16; ++i) {
        const int kk = i * 8 + kg;
        const float a = arow[kk];
        const float4 v = *reinterpret_cast<const float4*>(vbase + (size_t)kk * 1024);
        acc.x += a * v.x; acc.y += a * v.y; acc.z += a * v.z; acc.w += a * v.w;
    }
    __shared__ float sm2[8][128];
    *reinterpret_cast<float4*>(&sm2[kg][d4]) = acc;
    __syncthreads();
    if (t < 128) {
        float s0 = 0.f;
#pragma unroll
        for (int g = 0; g < 8; ++g) s0 += sm2[g][t];
        pctx[((size_t)bh * 32 + s) * 128 + t] = s0;
    }
}

// ---------- K6: reduce context partials ----------
__global__ __launch_bounds__(128) void ctx_reduce_kernel(
        const float* __restrict__ pctx, float* __restrict__ out) {
    const int bh = blockIdx.x;
    const int t = threadIdx.x;
    float acc = 0.f;
    for (int s2 = 0; s2 < 32; ++s2) acc += pctx[((size_t)bh * 32 + s2) * 128 + t];
    out[(size_t)bh * 128 + t] = acc;
}

extern "C" void kernel_launch(void* const* d_in, const int* in_sizes, int n_in,
                              void* d_out, int out_size, void* d_ws, size_t ws_size,
                              hipStream_t stream) {
    const float* query   = (const float*)d_in[0];
    const float* key_in  = (const float*)d_in[1];
    const float* value   = (const float*)d_in[2];
    const float* pa      = (const float*)d_in[3];
    const float* conv_w  = (const float*)d_in[4];
    const float* conv_b  = (const float*)d_in[5];
    const float* w_u     = (const float*)d_in[6];
    const float* w_q     = (const float*)d_in[7];
    const float* w_v     = (const float*)d_in[8];
    const float* bias    = (const float*)d_in[9];
    const float* score_w = (const float*)d_in[10];
    const float* score_b = (const float*)d_in[11];

    float* out = (float*)d_out;
    float* ctx_out = out;                 // [128,128]
    float* align_out = out + 16384;       // [16,8,4096]

    char* ws = (char*)d_ws;
    // small-scratch layout (always present)
    const size_t OFF_Q    = 0;                        // 64 KB
    const size_t OFF_LOC  = 65536;                    // 2.62 MB
    const size_t OFF_WVT  = OFF_LOC + 2621440;        // 2 MB
    const size_t OFF_PCTX = OFF_WVT + 2097152;        // 2 MB
    const size_t OFF_KBF  = OFF_PCTX + 2097152;       // 128 MB (optional)
    const size_t NEED_BF  = OFF_KBF + 134217728;

    float* ws_q            = (float*)(ws + OFF_Q);
    float* ws_loc          = (float*)(ws + OFF_LOC);
    unsigned short* ws_wvT = (unsigned short*)(ws + OFF_WVT);
    float* ws_pctx         = (float*)(ws + OFF_PCTX);
    unsigned short* ws_kbf = (unsigned short*)(ws + OFF_KBF);

    const bool pre = (ws_size >= NEED_BF);

    hipLaunchKernelGGL(wv_transpose_kernel, dim3(16, 16), dim3(256), 0, stream, w_v, ws_wvT);
    hipLaunchKernelGGL(qproj_kernel, dim3(128), dim3(128), 0, stream, query, w_q, ws_q);
    hipLaunchKernelGGL(loc_conv_kernel, dim3(16, 16), dim3(256), 0, stream, pa, conv_w, conv_b, ws_loc);
    if (pre) {
        hipLaunchKernelGGL(f32_to_bf16_kernel, dim3(2048), dim3(256), 0, stream,
                           key_in, ws_kbf, 8388608);
        hipLaunchKernelGGL((gemm_score_kernel<0>), dim3(4096), dim3(256), 0, stream,
                           key_in, ws_kbf, ws_wvT, ws_q, ws_loc, w_u, bias, score_w, score_b, align_out);
    } else {
        hipLaunchKernelGGL((gemm_score_kernel<1>), dim3(4096), dim3(256), 0, stream,
                           key_in, ws_kbf, ws_wvT, ws_q, ws_loc, w_u, bias, score_w, score_b, align_out);
    }
    hipLaunchKernelGGL(softmax_kernel, dim3(128), dim3(256), 0, stream, align_out);
    hipLaunchKernelGGL(ctx_partial_kernel, dim3(32, 128), dim3(256), 0, stream, value, align_out, ws_pctx);
    hipLaunchKernelGGL(ctx_reduce_kernel, dim3(128), dim3(128), 0, stream, ws_pctx, ctx_out);
}